// Round 11
// baseline (542.201 us; speedup 1.0000x reference)
//
#include <hip/hip_runtime.h>

// GRU: B=4096, T=512, I=32, H=64.
// R9: occupancy axis. (Round 10: verbatim resubmit — Round 9 proposal
// hit GPUAcquisitionTimeout, kernel never ran.)
// R8 post-mortem: moving x-proj post-barrier put its MFMAs on the
// critical chain (H-MFMAs accumulate into x-proj results) -> 247us
// regression; VALU issue cuts don't help (R7: -4 trans = -1.7%).
// The step is CHAIN-bound (~1110 cyc: barrier + ds_read + MFMA deps +
// epilogue chain), so the lever is covering the chain with an
// INDEPENDENTLY-PHASED neighbor, not shrinking it.
// R6 failed because its 8 waves shared ONE barrier (lockstep stalls).
// R9: 512 WGs x 4 waves, 8-batch tiles -> 2 independent WGs per CU =
// 2 waves/SIMD from DIFFERENT barrier groups; phases drift, so one WG's
// compute covers the other's barrier/LDS stall. MFMA B-operand uses 8
// of 16 cols; lanes 8-15 process duplicate batches (l&7) - bounded
// junk, self-consistent, no OOB; stores guarded to l<8. Extra MFMA/LDS/
// VALU demand is affordable (13%/32% busy).
// 2 waves/SIMD requires VGPR<=128: seq queue shrunk to 4-slot chunks
// (32 VGPR; prefetch distance 4 steps ~2000cyc >> 900cyc HBM; R6
// measured VGPR=80 at this sizing) + __launch_bounds__(256,2).
// Structure otherwise = R7 (237us best): pre-barrier x-proj, merged-rcp
// 5-trans epilogue, untracked asm loads, data-dep vmcnt drains, raw
// lgkmcnt+s_barrier.

#define TSTEPS 512
#define IDIM 32
#define HDIM 64

typedef __bf16 bf16x8 __attribute__((ext_vector_type(8)));
typedef __bf16 bf16x4 __attribute__((ext_vector_type(4)));
typedef float f32x4 __attribute__((ext_vector_type(4)));

#define NLOG2E -1.4426950408889634f
#define TWOLOG2E 2.8853900817779268f

// Two untracked 16B loads from base+literal offsets.
#define LOADPAIR(dst0, dst1, ptr, off)                                     \
    asm volatile("global_load_dwordx4 %0, %2, off offset:%c3\n\t"          \
                 "global_load_dwordx4 %1, %2, off offset:%c4"              \
        : "=&v"(dst0), "=&v"(dst1)                                         \
        : "v"(ptr), "i"(off), "i"((off) + 16));

// Issue one 4-timestep chunk (512 B contiguous per lane) as 8 untracked
// global_load_dwordx4. Stride between timesteps = IDIM*4 = 128 B.
#define ISSUE_CHUNK(qq, baseT) do {                                        \
    const float* _p = seqRow + (size_t)(baseT) * IDIM;                     \
    LOADPAIR(qq[0][0], qq[0][1], _p, 0)                                    \
    LOADPAIR(qq[1][0], qq[1][1], _p, 128)                                  \
    LOADPAIR(qq[2][0], qq[2][1], _p, 256)                                  \
    LOADPAIR(qq[3][0], qq[3][1], _p, 384)                                  \
} while (0)

// Drain the untracked loads; tie all destinations so no consumer can be
// scheduled above the wait (true data dependence).
#define WAITDEP(qq)                                                        \
    asm volatile("s_waitcnt vmcnt(0)"                                      \
        : "+v"(qq[0][0]), "+v"(qq[0][1]), "+v"(qq[1][0]), "+v"(qq[1][1]), \
          "+v"(qq[2][0]), "+v"(qq[2][1]), "+v"(qq[3][0]), "+v"(qq[3][1]))

// Raw barrier: LDS drained manually; NO vmcnt drain. "memory" clobber
// pins DS ops (esp. the hOut ds_write) on the correct side.
#define WG_BARRIER() do {                                                  \
    asm volatile("s_waitcnt lgkmcnt(0)" ::: "memory");                     \
    __builtin_amdgcn_s_barrier();                                          \
} while (0)

__global__ __launch_bounds__(256, 2) void gru_fused_kernel(
    const float* __restrict__ seq, const float* __restrict__ W_ih,
    const float* __restrict__ W_hh, const float* __restrict__ b_ih,
    const float* __restrict__ b_hh, float* __restrict__ out)
{
    __shared__ __bf16 hB[2][16][72];  // h^T double-buffered; 144 B row stride

    const int tid  = threadIdx.x;
    const int w    = tid >> 6;
    const int lane = tid & 63;
    const int l    = lane & 15;       // B-fragment col 0..15
    const int lb   = l & 7;           // real batch within 8-batch tile (cols 8-15 duplicate)
    const int q    = lane >> 4;       // quad
    const int b0   = blockIdx.x * 8;  // 8-batch tile

    for (int i = tid; i < 2 * 16 * 72; i += 256)
        (&hB[0][0][0])[i] = (__bf16)0.0f;

    // ---- A-fragments; r,z gates pre-scaled by -log2e; n gate by 2log2e ----
    bf16x8 aH[3][2], aI[3];
    #pragma unroll
    for (int g = 0; g < 3; ++g) {
        const float scl = (g < 2) ? NLOG2E : TWOLOG2E;
        const int row = g * 64 + w * 16 + l;
        #pragma unroll
        for (int kc = 0; kc < 2; ++kc) {
            const float* p = W_hh + row * HDIM + kc * 32 + q * 8;
            #pragma unroll
            for (int j = 0; j < 8; ++j) aH[g][kc][j] = (__bf16)(scl * p[j]);
        }
        const float* pi = W_ih + row * IDIM + q * 8;
        #pragma unroll
        for (int j = 0; j < 8; ++j) aI[g][j] = (__bf16)(scl * pi[j]);
    }

    // ---- bias C-init vectors at this lane's C/D rows (hidden = w*16+4q+r) ----
    f32x4 biasR4, biasZ4, biasXN4, biasHN4;
    #pragma unroll
    for (int r = 0; r < 4; ++r) {
        const int g = w * 16 + 4 * q + r;
        biasR4[r]  = NLOG2E * (b_ih[g]      + b_hh[g]);
        biasZ4[r]  = NLOG2E * (b_ih[64 + g] + b_hh[64 + g]);
        biasXN4[r] = TWOLOG2E * b_ih[128 + g];
        biasHN4[r] = TWOLOG2E * b_hh[128 + g];
    }

    float h[4] = {0.f, 0.f, 0.f, 0.f};

    // duplicate mapping: lanes with l>=8 load the same batch as l-8
    const float* seqRow = seq + ((size_t)(b0 + lb) * TSTEPS) * IDIM + q * 8;

    // ---- 4-step register queues, loaded ONLY via untracked asm loads.
    // qA = chunk [tc, tc+4), qB = chunk [tc+4, tc+8).
    f32x4 qA[4][2], qB[4][2];
    ISSUE_CHUNK(qA, 0);
    ISSUE_CHUNK(qB, 4);
    WAITDEP(qA);            // vmcnt(0): one-time drain of both chunks
    WAITDEP(qB);            // free (already 0); establishes qB data-dep

    WG_BARRIER();           // hB zero-init visible

    // ---- t=0 x-part (bias-init C) ----
    bf16x8 xb;
    #pragma unroll
    for (int j = 0; j < 4; ++j) {
        xb[j]     = (__bf16)qA[0][0][j];
        xb[4 + j] = (__bf16)qA[0][1][j];
    }
    f32x4 accR  = __builtin_amdgcn_mfma_f32_16x16x32_bf16(aI[0], xb, biasR4, 0, 0, 0);
    f32x4 accZ  = __builtin_amdgcn_mfma_f32_16x16x32_bf16(aI[1], xb, biasZ4, 0, 0, 0);
    f32x4 accXN = __builtin_amdgcn_mfma_f32_16x16x32_bf16(aI[2], xb, biasXN4, 0, 0, 0);

    for (int tc = 0; tc < TSTEPS; tc += 8) {
        #pragma unroll
        for (int s = 0; s < 8; ++s) {
            const int buf = s & 1;  // tc is a multiple of 8

            // post-barrier critical path: h^T fragments
            bf16x8 hb0 = *(const bf16x8*)&hB[buf][l][q * 8];
            bf16x8 hb1 = *(const bf16x8*)&hB[buf][l][32 + q * 8];

            // hb0 group then hb1 group (chains cover each other).
            accR = __builtin_amdgcn_mfma_f32_16x16x32_bf16(aH[0][0], hb0, accR, 0, 0, 0);
            accZ = __builtin_amdgcn_mfma_f32_16x16x32_bf16(aH[1][0], hb0, accZ, 0, 0, 0);
            f32x4 accHN = __builtin_amdgcn_mfma_f32_16x16x32_bf16(aH[2][0], hb0, biasHN4, 0, 0, 0);
            accR = __builtin_amdgcn_mfma_f32_16x16x32_bf16(aH[0][1], hb1, accR, 0, 0, 0);
            accZ = __builtin_amdgcn_mfma_f32_16x16x32_bf16(aH[1][1], hb1, accZ, 0, 0, 0);
            accHN = __builtin_amdgcn_mfma_f32_16x16x32_bf16(aH[2][1], hb1, accHN, 0, 0, 0);

            bf16x4 hOut;
            #pragma unroll
            for (int r = 0; r < 4; ++r) {
                // merged-rcp epilogue (R7): h' = [U(Z+h)+(h-Z)]/[(U+1)(Z+1)]
                const float R  = __builtin_amdgcn_exp2f(accR[r]);
                const float rg = __builtin_amdgcn_rcpf(R + 1.0f);
                const float v2 = __builtin_fmaf(rg, accHN[r], accXN[r]);
                const float U  = __builtin_amdgcn_exp2f(v2);
                const float Z  = __builtin_amdgcn_exp2f(accZ[r]);
                const float num = __builtin_fmaf(U, Z + h[r], h[r] - Z);
                const float den = (U + 1.0f) * (Z + 1.0f);
                h[r] = num * __builtin_amdgcn_rcpf(den);
                hOut[r] = (__bf16)h[r];
            }
            *(bf16x4*)&hB[buf ^ 1][l][w * 16 + 4 * q] = hOut;

            // burst pipeline: drain the chunk needed from the NEXT x-proj
            // (issued 4 steps ago, ~4x step cyc of cover), then issue ahead.
            if (s == 3) {
                WAITDEP(qB);                              // chunk tc+4 ready
                if (tc + 8 < TSTEPS) ISSUE_CHUNK(qA, tc + 8);
            }
            if (s == 7) {
                WAITDEP(qA);                              // chunk tc+8 ready
                if (tc + 12 < TSTEPS) ISSUE_CHUNK(qB, tc + 12);
            }

            // ---- pre-barrier work for t+1 (h-independent): cvt + x-proj MFMAs ----
            // s+1: slot in qA if <4 else qB; at s==7 uses qA[0] (refilled at
            // s==3, drained just above). Final step of the kernel computes a
            // dead x-proj from stale regs — harmless, results unused.
            {
                const int s1 = s + 1;
                const f32x4* x0 = (s1 < 4) ? &qA[s1 & 3][0]
                                           : (s1 < 8) ? &qB[s1 & 3][0]
                                                      : &qA[0][0];
                bf16x8 xb1;
                #pragma unroll
                for (int j = 0; j < 4; ++j) {
                    xb1[j]     = (__bf16)x0[0][j];
                    xb1[4 + j] = (__bf16)x0[1][j];
                }
                accR  = __builtin_amdgcn_mfma_f32_16x16x32_bf16(aI[0], xb1, biasR4, 0, 0, 0);
                accZ  = __builtin_amdgcn_mfma_f32_16x16x32_bf16(aI[1], xb1, biasZ4, 0, 0, 0);
                accXN = __builtin_amdgcn_mfma_f32_16x16x32_bf16(aI[2], xb1, biasXN4, 0, 0, 0);
            }

            WG_BARRIER();
        }
    }

    if (l < 8) {
        float4 o = {h[0], h[1], h[2], h[3]};
        *(float4*)&out[(size_t)(b0 + l) * HDIM + w * 16 + 4 * q] = o;
    }
}

extern "C" void kernel_launch(void* const* d_in, const int* in_sizes, int n_in,
                              void* d_out, int out_size, void* d_ws, size_t ws_size,
                              hipStream_t stream) {
    const float* seq  = (const float*)d_in[0];
    const float* W_ih = (const float*)d_in[1];
    const float* W_hh = (const float*)d_in[2];
    const float* b_ih = (const float*)d_in[3];
    const float* b_hh = (const float*)d_in[4];
    float* out = (float*)d_out;
    gru_fused_kernel<<<512, 256, 0, stream>>>(seq, W_ih, W_hh, b_ih, b_hh, out);
}